// Round 3
// baseline (127.590 us; speedup 1.0000x reference)
//
#include <hip/hip_runtime.h>
#include <math.h>

// Problem constants (from reference setup_inputs): B=65536, D=1024, C=4.
#define B_ROWS 65536
#define DIM    1024
#define NCON   4
#define NBLK   1024   // 4 waves/block -> 4096 waves -> exactly 16 rows/wave

typedef float vf4 __attribute__((ext_vector_type(4)));

// ---------------- single fused kernel ----------------
// Per-wave: normalize the 4 concept rows into registers (16 KB L2-broadcast,
// once per wave), stream 16 x-rows with non-temporal float4 loads, wave-reduce
// 5 dot products, softmax on lane 0. Final cross-block reduction is fused via
// the deterministic last-block-done pattern (agent-scope atomics: per-XCD L2s
// are not coherent, so plain stores/loads would race).
__global__ void __launch_bounds__(256, 4) sim_kernel(const float* __restrict__ x,
                                                     const float* __restrict__ tc,
                                                     const int*   __restrict__ flag_ptr,
                                                     float*       __restrict__ partials,
                                                     unsigned*    __restrict__ counter,
                                                     float*       __restrict__ out) {
    const int wid  = threadIdx.x >> 6;
    const int lane = threadIdx.x & 63;

    // --- load + normalize the 4 concept rows into per-lane registers ---
    vf4 t[NCON][4];
#pragma unroll
    for (int c = 0; c < NCON; ++c) {
        float ss = 0.f;
#pragma unroll
        for (int it = 0; it < 4; ++it) {
            t[c][it] = *reinterpret_cast<const vf4*>(tc + c * DIM + it * 256 + lane * 4);
            ss += t[c][it][0] * t[c][it][0] + t[c][it][1] * t[c][it][1]
                + t[c][it][2] * t[c][it][2] + t[c][it][3] * t[c][it][3];
        }
#pragma unroll
        for (int m = 32; m >= 1; m >>= 1) ss += __shfl_xor(ss, m);
        const float inv = 1.f / fmaxf(sqrtf(ss), 1e-12f);  // matches F.normalize eps clamp
#pragma unroll
        for (int it = 0; it < 4; ++it) t[c][it] *= inv;
    }

    const int flag = *flag_ptr;

    // --- main loop: software-pipelined non-temporal row stream ---
    constexpr int ROWS_PER_WAVE = B_ROWS / (NBLK * 4);          // 16, exact
    const int    gw      = blockIdx.x * 4 + wid;                 // global wave id
    const size_t rstride = (size_t)(NBLK * 4) * DIM;             // row stride between iters
    const float* xr      = x + (size_t)gw * DIM + lane * 4;      // this lane's base

    vf4 cur[4], nxt[4];
#pragma unroll
    for (int it = 0; it < 4; ++it)
        cur[it] = __builtin_nontemporal_load(reinterpret_cast<const vf4*>(xr + it * 256));

    float wsum = 0.f;
#pragma unroll 2
    for (int i = 0; i < ROWS_PER_WAVE; ++i) {
        if (i + 1 < ROWS_PER_WAVE) {
            const float* xn = xr + (size_t)(i + 1) * rstride;
#pragma unroll
            for (int it = 0; it < 4; ++it)
                nxt[it] = __builtin_nontemporal_load(reinterpret_cast<const vf4*>(xn + it * 256));
        }

        float acc0 = 0.f, acc1 = 0.f, acc2 = 0.f, acc3 = 0.f, xx = 0.f;
#pragma unroll
        for (int it = 0; it < 4; ++it) {
            const vf4 v = cur[it];
#pragma unroll
            for (int e = 0; e < 4; ++e) {
                xx   += v[e] * v[e];
                acc0 += v[e] * t[0][it][e];
                acc1 += v[e] * t[1][it][e];
                acc2 += v[e] * t[2][it][e];
                acc3 += v[e] * t[3][it][e];
            }
        }
#pragma unroll
        for (int m = 32; m >= 1; m >>= 1) {
            xx   += __shfl_xor(xx,   m);
            acc0 += __shfl_xor(acc0, m);
            acc1 += __shfl_xor(acc1, m);
            acc2 += __shfl_xor(acc2, m);
            acc3 += __shfl_xor(acc3, m);
        }
        if (lane == 0) {
            const float inv = 1.f / fmaxf(sqrtf(xx), 1e-12f);
            const float s0 = acc0 * inv, s1 = acc1 * inv, s2 = acc2 * inv, s3 = acc3 * inv;
            const float mx = fmaxf(fmaxf(s0, s1), fmaxf(s2, s3));
            const float e0 = __expf(s0 - mx), e1 = __expf(s1 - mx),
                        e2 = __expf(s2 - mx), e3 = __expf(s3 - mx);
            const float esum = e0 + e1 + e2 + e3;
            const float sel  = (flag == 0) ? e0 : (flag == 1) ? e1 : (flag == 2) ? e2 : e3;
            wsum += sel / esum;
        }

        if (i + 1 < ROWS_PER_WAVE) {
#pragma unroll
            for (int it = 0; it < 4; ++it) cur[it] = nxt[it];
        }
    }

    // --- block partial + last-block-done final reduction ---
    __shared__ float ls[4];
    __shared__ bool  amLast;
    if (lane == 0) ls[wid] = wsum;
    __syncthreads();
    if (threadIdx.x == 0) {
        const float p = ls[0] + ls[1] + ls[2] + ls[3];
        __hip_atomic_store(&partials[blockIdx.x], p, __ATOMIC_RELEASE, __HIP_MEMORY_SCOPE_AGENT);
        const unsigned old = __hip_atomic_fetch_add(counter, 1u, __ATOMIC_ACQ_REL, __HIP_MEMORY_SCOPE_AGENT);
        amLast = (old == NBLK - 1);
    }
    __syncthreads();
    if (!amLast) return;

    // last block: deterministic fixed-order reduction of the 1024 partials
    double s = 0.0;
    for (int i = threadIdx.x; i < NBLK; i += 256)
        s += (double)__hip_atomic_load(&partials[i], __ATOMIC_RELAXED, __HIP_MEMORY_SCOPE_AGENT);
    __shared__ double ds[256];
    ds[threadIdx.x] = s;
    __syncthreads();
    for (int st = 128; st >= 1; st >>= 1) {
        if (threadIdx.x < st) ds[threadIdx.x] += ds[threadIdx.x + st];
        __syncthreads();
    }
    if (threadIdx.x == 0) out[0] = (float)(ds[0] / (double)B_ROWS);
}

extern "C" void kernel_launch(void* const* d_in, const int* in_sizes, int n_in,
                              void* d_out, int out_size, void* d_ws, size_t ws_size,
                              hipStream_t stream) {
    // inputs (setup_inputs order): x[B,D] f32, label[B] int (UNUSED), text_concept[4,D] f32, concept_flag scalar int
    const float* x    = (const float*)d_in[0];
    const float* tc   = (const float*)d_in[2];
    const int*   flag = (const int*)d_in[3];
    float* out = (float*)d_out;

    float*    partials = (float*)d_ws;                    // 1024 floats = 4 KB
    unsigned* counter  = (unsigned*)((char*)d_ws + 4096); // 4 bytes

    hipMemsetAsync(counter, 0, sizeof(unsigned), stream); // ws is poisoned 0xAA; re-zeroed every replay
    sim_kernel<<<NBLK, 256, 0, stream>>>(x, tc, flag, partials, counter, out);
}

// Round 4
// 48.362 us; speedup vs baseline: 2.6382x; 2.6382x over previous
//
#include <hip/hip_runtime.h>
#include <math.h>

// Problem constants (from reference setup_inputs): B=65536, D=1024, C=4.
#define B_ROWS 65536
#define DIM    1024
#define NCON   4
#define NBLK   1024   // 4 waves/block -> 4096 waves -> exactly 16 rows/wave

// ---------------- kernel 1: per-row cosine sims + softmax + partial sums ----------------
// (identical to the round-2 kernel that measured 49.6 us total; no nt hints,
//  no device-scope atomics — both implicated in the round-3 regression)
__global__ void __launch_bounds__(256, 4) sim_kernel(const float* __restrict__ x,
                                                     const float* __restrict__ tc,
                                                     const int*   __restrict__ flag_ptr,
                                                     float*       __restrict__ partials) {
    const int wid  = threadIdx.x >> 6;
    const int lane = threadIdx.x & 63;

    // --- load + normalize the 4 concept rows into per-lane registers ---
    float4 t[NCON][4];
#pragma unroll
    for (int c = 0; c < NCON; ++c) {
        float ss = 0.f;
#pragma unroll
        for (int it = 0; it < 4; ++it) {
            t[c][it] = *reinterpret_cast<const float4*>(tc + c * DIM + it * 256 + lane * 4);
            ss += t[c][it].x * t[c][it].x + t[c][it].y * t[c][it].y
                + t[c][it].z * t[c][it].z + t[c][it].w * t[c][it].w;
        }
#pragma unroll
        for (int m = 32; m >= 1; m >>= 1) ss += __shfl_xor(ss, m);
        const float inv = 1.f / fmaxf(sqrtf(ss), 1e-12f);  // matches F.normalize eps clamp
#pragma unroll
        for (int it = 0; it < 4; ++it) {
            t[c][it].x *= inv; t[c][it].y *= inv; t[c][it].z *= inv; t[c][it].w *= inv;
        }
    }

    const int flag = *flag_ptr;

    // --- main loop: software-pipelined row stream ---
    constexpr int ROWS_PER_WAVE = B_ROWS / (NBLK * 4);          // 16, exact
    const int    gw      = blockIdx.x * 4 + wid;                 // global wave id
    const size_t rstride = (size_t)(NBLK * 4) * DIM;             // row stride between iters
    const float* xr      = x + (size_t)gw * DIM + lane * 4;      // this lane's base

    float4 cur[4], nxt[4];
#pragma unroll
    for (int it = 0; it < 4; ++it)
        cur[it] = *reinterpret_cast<const float4*>(xr + it * 256);

    float wsum = 0.f;
#pragma unroll 2
    for (int i = 0; i < ROWS_PER_WAVE; ++i) {
        // prefetch next row while we compute/reduce the current one
        if (i + 1 < ROWS_PER_WAVE) {
            const float* xn = xr + (size_t)(i + 1) * rstride;
#pragma unroll
            for (int it = 0; it < 4; ++it)
                nxt[it] = *reinterpret_cast<const float4*>(xn + it * 256);
        }

        float acc0 = 0.f, acc1 = 0.f, acc2 = 0.f, acc3 = 0.f, xx = 0.f;
#pragma unroll
        for (int it = 0; it < 4; ++it) {
            const float4 v = cur[it];
            xx   += v.x * v.x        + v.y * v.y        + v.z * v.z        + v.w * v.w;
            acc0 += v.x * t[0][it].x + v.y * t[0][it].y + v.z * t[0][it].z + v.w * t[0][it].w;
            acc1 += v.x * t[1][it].x + v.y * t[1][it].y + v.z * t[1][it].z + v.w * t[1][it].w;
            acc2 += v.x * t[2][it].x + v.y * t[2][it].y + v.z * t[2][it].z + v.w * t[2][it].w;
            acc3 += v.x * t[3][it].x + v.y * t[3][it].y + v.z * t[3][it].z + v.w * t[3][it].w;
        }
        // wave-wide reduction of the 5 accumulators (64 lanes)
#pragma unroll
        for (int m = 32; m >= 1; m >>= 1) {
            xx   += __shfl_xor(xx,   m);
            acc0 += __shfl_xor(acc0, m);
            acc1 += __shfl_xor(acc1, m);
            acc2 += __shfl_xor(acc2, m);
            acc3 += __shfl_xor(acc3, m);
        }
        if (lane == 0) {
            const float inv = 1.f / fmaxf(sqrtf(xx), 1e-12f);
            const float s0 = acc0 * inv, s1 = acc1 * inv, s2 = acc2 * inv, s3 = acc3 * inv;
            const float mx = fmaxf(fmaxf(s0, s1), fmaxf(s2, s3));
            const float e0 = __expf(s0 - mx), e1 = __expf(s1 - mx),
                        e2 = __expf(s2 - mx), e3 = __expf(s3 - mx);
            const float esum = e0 + e1 + e2 + e3;
            const float sel  = (flag == 0) ? e0 : (flag == 1) ? e1 : (flag == 2) ? e2 : e3;
            wsum += sel / esum;
        }

        if (i + 1 < ROWS_PER_WAVE) {
#pragma unroll
            for (int it = 0; it < 4; ++it) cur[it] = nxt[it];
        }
    }

    __shared__ float ls[4];
    if (lane == 0) ls[wid] = wsum;
    __syncthreads();
    if (threadIdx.x == 0) partials[blockIdx.x] = ls[0] + ls[1] + ls[2] + ls[3];
}

// ---------------- kernel 2: single-wave deterministic final reduction ----------------
// 64 threads, float4 loads (4 x 1KB coalesced instrs), fixed-order double sum,
// shuffle-only butterfly (no LDS, no __syncthreads) -> bitwise-deterministic.
__global__ void __launch_bounds__(64) reduce_kernel(const float* __restrict__ partials,
                                                    float* __restrict__ out) {
    const int lane = threadIdx.x;   // 0..63
    double s = 0.0;
#pragma unroll
    for (int j = 0; j < 4; ++j) {
        const float4 v = *reinterpret_cast<const float4*>(partials + j * 256 + lane * 4);
        s += (double)v.x + (double)v.y + (double)v.z + (double)v.w;
    }
#pragma unroll
    for (int m = 32; m >= 1; m >>= 1) s += __shfl_xor(s, m);
    if (lane == 0) out[0] = (float)(s / (double)B_ROWS);
}

extern "C" void kernel_launch(void* const* d_in, const int* in_sizes, int n_in,
                              void* d_out, int out_size, void* d_ws, size_t ws_size,
                              hipStream_t stream) {
    // inputs (setup_inputs order): x[B,D] f32, label[B] int (UNUSED), text_concept[4,D] f32, concept_flag scalar int
    const float* x    = (const float*)d_in[0];
    const float* tc   = (const float*)d_in[2];
    const int*   flag = (const int*)d_in[3];
    float* out = (float*)d_out;

    float* partials = (float*)d_ws;   // 1024 floats = 4 KB

    sim_kernel<<<NBLK, 256, 0, stream>>>(x, tc, flag, partials);
    reduce_kernel<<<1, 64, 0, stream>>>(partials, out);
}